// Round 2
// baseline (759.143 us; speedup 1.0000x reference)
//
#include <hip/hip_runtime.h>

typedef _Float16 f16;
typedef _Float16 f16x8 __attribute__((ext_vector_type(8)));
typedef _Float16 f16x4 __attribute__((ext_vector_type(4)));
typedef float    f32x4 __attribute__((ext_vector_type(4)));

#define MFMA16(a,b,c) __builtin_amdgcn_mfma_f32_16x16x32_f16(a,b,c,0,0,0)

static constexpr float NEGV = -1e9f;
static constexpr float SC   = 0.05f;   // 1/SCALE = 1/20

__device__ __forceinline__ void gload16(const void* g, void* l){
    __builtin_amdgcn_global_load_lds(
        (const __attribute__((address_space(1))) void*)g,
        (__attribute__((address_space(3))) void*)l, 16, 0, 0);
}

// ---------------- f32 -> f16 convert ----------------
__global__ __launch_bounds__(256) void cvt_kernel(const float* __restrict__ in,
                                                  f16* __restrict__ out, int n){
    int i = (blockIdx.x*256 + threadIdx.x)*4;
    if (i < n){
        float4 v = *reinterpret_cast<const float4*>(in + i);
        f16x4 o = { (f16)v.x, (f16)v.y, (f16)v.z, (f16)v.w };
        *reinterpret_cast<f16x4*>(out + i) = o;
    }
}

// ---------------- QKV projection: C[m,n] = sum_k X[m,k]*W[n,k] + b[n] ----------------
// z=0 -> Q [bh][s][192], z=1 -> K [bh][s][192], z=2 -> V transposed [bh][192][s]
__global__ __launch_bounds__(256) void proj_kernel(
    const f16* __restrict__ xb, const f16* __restrict__ Wb,
    const float* __restrict__ bq, const float* __restrict__ bk, const float* __restrict__ bv,
    f16* __restrict__ Qb, f16* __restrict__ Kb, f16* __restrict__ Vt)
{
    __shared__ f16 As[128*32];
    __shared__ f16 Bs[128*32];
    const int z = blockIdx.z;
    const f16*   Wz   = Wb + (size_t)z*768*768;
    const float* bias = (z==0) ? bq : (z==1 ? bk : bv);
    f16*         out  = (z==0) ? Qb : (z==1 ? Kb : Vt);
    const int row0 = blockIdx.y*128, n0 = blockIdx.x*128;
    const int tid = threadIdx.x, w = tid>>6, l = tid&63;
    const int wm = w>>1, wn = w&1, c = l&15, g = l>>4;
    f32x4 zero = {0.f,0.f,0.f,0.f};
    f32x4 acc[4][4];
    for (int i=0;i<4;i++) for (int j=0;j<4;j++) acc[i][j] = zero;

    const f16* ag = xb + (size_t)(row0 + w*32 + (l>>2))*768 + (l&3)*8;
    const f16* bg = Wz + (size_t)(n0   + w*32 + (l>>2))*768 + (l&3)*8;
    f16* asd = As + w*1024;
    f16* bsd = Bs + w*1024;

    for (int k0 = 0; k0 < 768; k0 += 32){
        __syncthreads();
        gload16(ag + k0,          asd      );
        gload16(ag + k0 + 16*768, asd + 512);
        gload16(bg + k0,          bsd      );
        gload16(bg + k0 + 16*768, bsd + 512);
        __syncthreads();
        f16x8 af[4], bf[4];
        for (int mt=0; mt<4; mt++)
            af[mt] = *reinterpret_cast<const f16x8*>(As + (wm*64 + mt*16 + c)*32 + g*8);
        for (int nt=0; nt<4; nt++)
            bf[nt] = *reinterpret_cast<const f16x8*>(Bs + (wn*64 + nt*16 + c)*32 + g*8);
        for (int mt=0; mt<4; mt++)
            for (int nt=0; nt<4; nt++)
                acc[mt][nt] = MFMA16(af[mt], bf[nt], acc[mt][nt]);
    }

    for (int nt=0; nt<4; nt++){
        int nb = n0 + wn*64 + nt*16;
        int h  = nb/192;
        int d  = (nb - h*192) + c;
        float bv_ = bias[nb + c];
        for (int mt=0; mt<4; mt++){
            int mb = row0 + wm*64 + mt*16 + g*4;
            if (z < 2){
                for (int r=0;r<4;r++){
                    int m = mb + r; int bi = m>>11, s = m&2047;
                    out[(size_t)((bi*4 + h)*2048 + s)*192 + d] = (f16)(acc[mt][nt][r] + bv_);
                }
            } else {
                int bi = mb>>11, s0 = mb&2047;
                f16x4 pk = { (f16)(acc[mt][nt][0] + bv_), (f16)(acc[mt][nt][1] + bv_),
                             (f16)(acc[mt][nt][2] + bv_), (f16)(acc[mt][nt][3] + bv_) };
                *reinterpret_cast<f16x4*>(&out[(size_t)((bi*4 + h)*192 + d)*2048 + s0]) = pk;
            }
        }
    }
}

// ---------------- pass 1: per-column (k) softmax stats over q >= k ----------------
__global__ __launch_bounds__(256) void colstats_kernel(
    const f16* __restrict__ Qb, const f16* __restrict__ Kb,
    const unsigned char* __restrict__ am,
    float* __restrict__ Mst, float* __restrict__ Lst)
{
    const int bh = blockIdx.y, b = bh>>2;
    const int w = threadIdx.x>>6, l = threadIdx.x&63;
    const int c = l&15, g = l>>4;
    const int kt = blockIdx.x*64 + w*16;
    const f16* Qh = Qb + (size_t)bh*2048*192;
    const f16* Kh = Kb + (size_t)bh*2048*192;
    const unsigned char* amb = am + b*2048;

    f16x8 kf[6];
    for (int ds=0; ds<6; ds++)
        kf[ds] = *reinterpret_cast<const f16x8*>(Kh + (size_t)(kt + c)*192 + ds*32 + g*8);

    float M = -1e38f, L = 0.f;
    f32x4 zero = {0.f,0.f,0.f,0.f};
    for (int j = kt>>4; j < 128; j++){
        int q0 = j<<4;
        f32x4 sacc = zero;
        for (int ds=0; ds<6; ds++){
            f16x8 qf = *reinterpret_cast<const f16x8*>(Qh + (size_t)(q0 + c)*192 + ds*32 + g*8);
            sacc = MFMA16(qf, kf[ds], sacc);
        }
        float sv[4]; float m4 = -1e38f;
        for (int r=0;r<4;r++){
            int q = q0 + g*4 + r;
            float v = sacc[r]*SC;
            if (amb[q]) v = NEGV;
            if (q < kt + c) v = -1e38f;   // causal-invalid: contributes 0
            sv[r] = v; m4 = fmaxf(m4, v);
        }
        m4 = fmaxf(m4, __shfl_xor(m4, 16));
        m4 = fmaxf(m4, __shfl_xor(m4, 32));
        float Mn = fmaxf(M, m4);
        float p = __expf(sv[0]-Mn) + __expf(sv[1]-Mn) + __expf(sv[2]-Mn) + __expf(sv[3]-Mn);
        p += __shfl_xor(p, 16);
        p += __shfl_xor(p, 32);
        L = L*__expf(M - Mn) + p;
        M = Mn;
    }
    if (l < 16){
        Mst[bh*2048 + kt + l] = M;
        Lst[bh*2048 + kt + l] = 1.f/L;
    }
}

// ---------------- pass 2: x1[q,:] = sum_{k<=q} exp(s-M[k])*invL[k] * V[k,:] ----------------
__global__ __launch_bounds__(256) void attn_kernel(
    const f16* __restrict__ Qb, const f16* __restrict__ Kb, const f16* __restrict__ Vt,
    const float* __restrict__ Mst, const float* __restrict__ Lst,
    const unsigned char* __restrict__ am,
    float* __restrict__ x1)
{
    __shared__ f16 Pl[4*1024];   // per-wave 16x64 fp16, XOR-swizzled
    const int bh = blockIdx.y, b = bh>>2, h = bh&3;
    const int qb = blockIdx.x;
    const int w = threadIdx.x>>6, l = threadIdx.x&63;
    const int c = l&15, g = l>>4;
    const int qw = qb*64 + w*16;
    const f16* Qh = Qb + (size_t)bh*2048*192;
    const f16* Kh = Kb + (size_t)bh*2048*192;
    const f16* Vh = Vt + (size_t)bh*192*2048;
    const float* Mh = Mst + bh*2048;
    const float* Lh = Lst + bh*2048;
    char* Pb = (char*)(Pl + w*1024);

    f16x8 qf[6];
    for (int ds=0; ds<6; ds++)
        qf[ds] = *reinterpret_cast<const f16x8*>(Qh + (size_t)(qw + c)*192 + ds*32 + g*8);
    bool pm[4];
    for (int r=0;r<4;r++) pm[r] = am[b*2048 + qw + g*4 + r] != 0;

    f32x4 zero = {0.f,0.f,0.f,0.f};
    f32x4 acc[12];
    for (int i=0;i<12;i++) acc[i] = zero;

    for (int kb=0; kb<=qb; kb++){
        int k0 = kb*64;
        bool diag = (kb == qb);
        for (int kt2=0; kt2<4; kt2++){
            int kk = k0 + kt2*16;
            f32x4 sacc = zero;
            for (int ds=0; ds<6; ds++){
                f16x8 kf = *reinterpret_cast<const f16x8*>(Kh + (size_t)(kk + c)*192 + ds*32 + g*8);
                sacc = MFMA16(qf[ds], kf, sacc);
            }
            float Mk = Mh[kk + c], iL = Lh[kk + c];
            for (int r=0;r<4;r++){
                int q = qw + g*4 + r;
                float v = sacc[r]*SC;
                if (pm[r]) v = NEGV;
                float p = __expf(v - Mk)*iL;
                if (diag && (kk + c > q)) p = 0.f;
                int row = g*4 + r;
                int byo = (row*128 + (kt2*16 + c)*2) ^ ((row&7)<<4);
                *reinterpret_cast<f16*>(Pb + byo) = (f16)p;
            }
        }
        for (int ks=0; ks<2; ks++){
            int byo = (c*128 + ks*64 + g*16) ^ ((c&7)<<4);
            f16x8 pa = *reinterpret_cast<const f16x8*>(Pb + byo);
            for (int dt=0; dt<12; dt++){
                f16x8 vb = *reinterpret_cast<const f16x8*>(Vh + (size_t)(dt*16 + c)*2048 + k0 + ks*32 + g*8);
                acc[dt] = MFMA16(pa, vb, acc[dt]);
            }
        }
    }
    for (int dt=0; dt<12; dt++){
        int d = h*192 + dt*16 + c;
        for (int r=0;r<4;r++){
            int q = qw + g*4 + r;
            x1[(size_t)(b*2048 + q)*768 + d] = acc[dt][r];
        }
    }
}

// ---------------- residual + layernorm ----------------
__global__ __launch_bounds__(256) void ln_kernel(
    const float* __restrict__ x, const float* __restrict__ x1,
    const float* __restrict__ gamma, const float* __restrict__ beta,
    float* __restrict__ out)
{
    const int r = blockIdx.x, t = threadIdx.x;
    const float* xr = x  + (size_t)r*768;
    const float* yr = x1 + (size_t)r*768;
    float v[3]; float s1 = 0.f, s2 = 0.f;
    for (int i=0;i<3;i++){ int j = t + i*256; float y = xr[j] + yr[j]; v[i]=y; s1+=y; s2+=y*y; }
    for (int o=32;o>=1;o>>=1){ s1 += __shfl_xor(s1,o); s2 += __shfl_xor(s2,o); }
    __shared__ float a1[4], a2[4];
    if ((t&63)==0){ a1[t>>6]=s1; a2[t>>6]=s2; }
    __syncthreads();
    s1 = a1[0]+a1[1]+a1[2]+a1[3];
    s2 = a2[0]+a2[1]+a2[2]+a2[3];
    float mu  = s1*(1.f/768.f);
    float var = s2*(1.f/768.f) - mu*mu;
    float rs  = rsqrtf(var + 1e-5f);
    for (int i=0;i<3;i++){
        int j = t + i*256;
        out[(size_t)r*768 + j] = (v[i]-mu)*rs*gamma[j] + beta[j];
    }
}

extern "C" void kernel_launch(void* const* d_in, const int* in_sizes, int n_in,
                              void* d_out, int out_size, void* d_ws, size_t ws_size,
                              hipStream_t stream)
{
    const float* x     = (const float*)d_in[0];
    const unsigned char* am = (const unsigned char*)d_in[1];
    const float* Wq    = (const float*)d_in[2];
    const float* bq    = (const float*)d_in[3];
    const float* Wk    = (const float*)d_in[4];
    const float* bk    = (const float*)d_in[5];
    const float* Wv    = (const float*)d_in[6];
    const float* bv    = (const float*)d_in[7];
    const float* gamma = (const float*)d_in[8];
    const float* beta  = (const float*)d_in[9];
    float* out = (float*)d_out;

    f16* xb  = (f16*)d_ws;
    f16* Wb  = xb + (size_t)8192*768;          // 3 weight matrices fp16
    f16* Qb  = Wb + (size_t)3*768*768;
    f16* Kb  = Qb + (size_t)16*2048*192;
    f16* Vt  = Kb + (size_t)16*2048*192;
    float* Mst = (float*)(Vt + (size_t)16*2048*192);
    float* Lst = Mst + 16*2048;
    float* x1  = Lst + 16*2048;

    cvt_kernel<<<6144, 256, 0, stream>>>(x,  xb, 8192*768);
    cvt_kernel<<<576,  256, 0, stream>>>(Wq, Wb,            589824);
    cvt_kernel<<<576,  256, 0, stream>>>(Wk, Wb + 589824,   589824);
    cvt_kernel<<<576,  256, 0, stream>>>(Wv, Wb + 2*589824, 589824);
    proj_kernel<<<dim3(6,64,3), 256, 0, stream>>>(xb, Wb, bq, bk, bv, Qb, Kb, Vt);
    colstats_kernel<<<dim3(32,16), 256, 0, stream>>>(Qb, Kb, am, Mst, Lst);
    attn_kernel<<<dim3(32,16), 256, 0, stream>>>(Qb, Kb, Vt, Mst, Lst, am, x1);
    ln_kernel<<<8192, 256, 0, stream>>>(x, x1, gamma, beta, out);
}

// Round 3
// 727.941 us; speedup vs baseline: 1.0429x; 1.0429x over previous
//
#include <hip/hip_runtime.h>

typedef _Float16 f16;
typedef _Float16 f16x8 __attribute__((ext_vector_type(8)));
typedef _Float16 f16x4 __attribute__((ext_vector_type(4)));
typedef float    f32x4 __attribute__((ext_vector_type(4)));

#define MFMA16(a,b,c) __builtin_amdgcn_mfma_f32_16x16x32_f16(a,b,c,0,0,0)

static constexpr float NEGV = -1e9f;
static constexpr float SC   = 0.05f;   // 1/SCALE = 1/20

__device__ __forceinline__ void gload16(const void* g, void* l){
    __builtin_amdgcn_global_load_lds(
        (const __attribute__((address_space(1))) void*)g,
        (__attribute__((address_space(3))) void*)l, 16, 0, 0);
}

// ---------------- f32 -> f16 convert ----------------
__global__ __launch_bounds__(256) void cvt_kernel(const float* __restrict__ in,
                                                  f16* __restrict__ out, int n){
    int i = (blockIdx.x*256 + threadIdx.x)*4;
    if (i < n){
        float4 v = *reinterpret_cast<const float4*>(in + i);
        f16x4 o = { (f16)v.x, (f16)v.y, (f16)v.z, (f16)v.w };
        *reinterpret_cast<f16x4*>(out + i) = o;
    }
}

// ---------------- zero-init f32 buffer ----------------
__global__ __launch_bounds__(256) void zero_kernel(float* __restrict__ p, int n){
    int i = (blockIdx.x*256 + threadIdx.x)*4;
    if (i < n){
        float4 z = {0.f,0.f,0.f,0.f};
        *reinterpret_cast<float4*>(p + i) = z;
    }
}

// ---------------- QKV projection: C[m,n] = sum_k X[m,k]*W[n,k] + b[n] ----------------
// z=0 -> Q [bh][s][192], z=1 -> K [bh][s][192], z=2 -> V transposed [bh][192][s]
__global__ __launch_bounds__(256) void proj_kernel(
    const f16* __restrict__ xb, const f16* __restrict__ Wb,
    const float* __restrict__ bq, const float* __restrict__ bk, const float* __restrict__ bv,
    f16* __restrict__ Qb, f16* __restrict__ Kb, f16* __restrict__ Vt)
{
    __shared__ f16 As[128*32];
    __shared__ f16 Bs[128*32];
    const int z = blockIdx.z;
    const f16*   Wz   = Wb + (size_t)z*768*768;
    const float* bias = (z==0) ? bq : (z==1 ? bk : bv);
    f16*         out  = (z==0) ? Qb : (z==1 ? Kb : Vt);
    const int row0 = blockIdx.y*128, n0 = blockIdx.x*128;
    const int tid = threadIdx.x, w = tid>>6, l = tid&63;
    const int wm = w>>1, wn = w&1, c = l&15, g = l>>4;
    f32x4 zero = {0.f,0.f,0.f,0.f};
    f32x4 acc[4][4];
    for (int i=0;i<4;i++) for (int j=0;j<4;j++) acc[i][j] = zero;

    const f16* ag = xb + (size_t)(row0 + w*32 + (l>>2))*768 + (l&3)*8;
    const f16* bg = Wz + (size_t)(n0   + w*32 + (l>>2))*768 + (l&3)*8;
    f16* asd = As + w*1024;
    f16* bsd = Bs + w*1024;

    for (int k0 = 0; k0 < 768; k0 += 32){
        __syncthreads();
        gload16(ag + k0,          asd      );
        gload16(ag + k0 + 16*768, asd + 512);
        gload16(bg + k0,          bsd      );
        gload16(bg + k0 + 16*768, bsd + 512);
        __syncthreads();
        f16x8 af[4], bf[4];
        for (int mt=0; mt<4; mt++)
            af[mt] = *reinterpret_cast<const f16x8*>(As + (wm*64 + mt*16 + c)*32 + g*8);
        for (int nt=0; nt<4; nt++)
            bf[nt] = *reinterpret_cast<const f16x8*>(Bs + (wn*64 + nt*16 + c)*32 + g*8);
        for (int mt=0; mt<4; mt++)
            for (int nt=0; nt<4; nt++)
                acc[mt][nt] = MFMA16(af[mt], bf[nt], acc[mt][nt]);
    }

    for (int nt=0; nt<4; nt++){
        int nb = n0 + wn*64 + nt*16;
        int h  = nb/192;
        int d  = (nb - h*192) + c;
        float bv_ = bias[nb + c];
        for (int mt=0; mt<4; mt++){
            int mb = row0 + wm*64 + mt*16 + g*4;
            if (z < 2){
                for (int r=0;r<4;r++){
                    int m = mb + r; int bi = m>>11, s = m&2047;
                    out[(size_t)((bi*4 + h)*2048 + s)*192 + d] = (f16)(acc[mt][nt][r] + bv_);
                }
            } else {
                int bi = mb>>11, s0 = mb&2047;
                f16x4 pk = { (f16)(acc[mt][nt][0] + bv_), (f16)(acc[mt][nt][1] + bv_),
                             (f16)(acc[mt][nt][2] + bv_), (f16)(acc[mt][nt][3] + bv_) };
                *reinterpret_cast<f16x4*>(&out[(size_t)((bi*4 + h)*192 + d)*2048 + s0]) = pk;
            }
        }
    }
}

// ---------------- pass 1: per-column (k) partial softmax stats over a q-chunk ----------------
// grid (kb=32, ch=8, bh=16). Partial (M, L) per 256-wide q-chunk.
__global__ __launch_bounds__(256) void colstats_kernel(
    const f16* __restrict__ Qb, const f16* __restrict__ Kb,
    const unsigned char* __restrict__ am,
    float* __restrict__ Mp, float* __restrict__ Lp)
{
    const int bh = blockIdx.z, b = bh>>2;
    const int ch = blockIdx.y;
    const int w = threadIdx.x>>6, l = threadIdx.x&63;
    const int c = l&15, g = l>>4;
    const int kt = blockIdx.x*64 + w*16;
    const f16* Qh = Qb + (size_t)bh*2048*192;
    const f16* Kh = Kb + (size_t)bh*2048*192;
    const unsigned char* amb = am + b*2048;

    float M = -1e38f, L = 0.f;
    const int jstart = max(ch*16, kt>>4), jend = ch*16 + 16;

    if (jstart < jend){
        f16x8 kf[6];
        for (int ds=0; ds<6; ds++)
            kf[ds] = *reinterpret_cast<const f16x8*>(Kh + (size_t)(kt + c)*192 + ds*32 + g*8);

        f32x4 zero = {0.f,0.f,0.f,0.f};
        for (int j = jstart; j < jend; j++){
            int q0 = j<<4;
            f32x4 sacc = zero;
            for (int ds=0; ds<6; ds++){
                f16x8 qf = *reinterpret_cast<const f16x8*>(Qh + (size_t)(q0 + c)*192 + ds*32 + g*8);
                sacc = MFMA16(qf, kf[ds], sacc);
            }
            float sv[4]; float m4 = -1e38f;
            for (int r=0;r<4;r++){
                int q = q0 + g*4 + r;
                float v = sacc[r]*SC;
                if (amb[q]) v = NEGV;
                if (q < kt + c) v = -1e38f;   // causal-invalid: contributes 0
                sv[r] = v; m4 = fmaxf(m4, v);
            }
            m4 = fmaxf(m4, __shfl_xor(m4, 16));
            m4 = fmaxf(m4, __shfl_xor(m4, 32));
            float Mn = fmaxf(M, m4);
            float p = __expf(sv[0]-Mn) + __expf(sv[1]-Mn) + __expf(sv[2]-Mn) + __expf(sv[3]-Mn);
            p += __shfl_xor(p, 16);
            p += __shfl_xor(p, 32);
            L = L*__expf(M - Mn) + p;
            M = Mn;
        }
    }
    if (l < 16){
        size_t o = ((size_t)bh*8 + ch)*2048 + kt + l;
        Mp[o] = M;
        Lp[o] = L;
    }
}

// ---------------- combine chunk partials -> M, 1/L ----------------
__global__ __launch_bounds__(256) void combine_kernel(
    const float* __restrict__ Mp, const float* __restrict__ Lp,
    float* __restrict__ Mst, float* __restrict__ Lst)
{
    int idx = blockIdx.x*256 + threadIdx.x;   // 16*2048
    int bh = idx >> 11, col = idx & 2047;
    float m[8];
    float M = -1e38f;
    for (int ch=0; ch<8; ch++){
        m[ch] = Mp[((size_t)bh*8 + ch)*2048 + col];
        M = fmaxf(M, m[ch]);
    }
    float L = 0.f;
    for (int ch=0; ch<8; ch++)
        L += Lp[((size_t)bh*8 + ch)*2048 + col] * __expf(m[ch] - M);
    Mst[(size_t)bh*2048 + col] = M;
    Lst[(size_t)bh*2048 + col] = 1.f/L;
}

// ---------------- pass 2: x1[q,:] += sum_{k in chunk, k<=q} exp(s-M[k])*invL[k] * V[k,:] ----------------
// grid (qb=32, ch=8, bh=16); atomic f32 accumulation into x1.
__global__ __launch_bounds__(256) void attn_kernel(
    const f16* __restrict__ Qb, const f16* __restrict__ Kb, const f16* __restrict__ Vt,
    const float* __restrict__ Mst, const float* __restrict__ Lst,
    const unsigned char* __restrict__ am,
    float* __restrict__ x1)
{
    __shared__ f16 Pl[4*1024];   // per-wave 16x64 fp16, XOR-swizzled
    const int bh = blockIdx.z, b = bh>>2, h = bh&3;
    const int qb = blockIdx.x;
    const int ch = blockIdx.y;
    if (ch*256 > qb*64 + 63) return;          // chunk entirely above diagonal
    const int w = threadIdx.x>>6, l = threadIdx.x&63;
    const int c = l&15, g = l>>4;
    const int qw = qb*64 + w*16;
    if (ch*256 > qw + 15) return;             // this wave has no valid k in chunk
    const f16* Qh = Qb + (size_t)bh*2048*192;
    const f16* Kh = Kb + (size_t)bh*2048*192;
    const f16* Vh = Vt + (size_t)bh*192*2048;
    const float* Mh = Mst + (size_t)bh*2048;
    const float* Lh = Lst + (size_t)bh*2048;
    char* Pb = (char*)(Pl + w*1024);

    f16x8 qf[6];
    for (int ds=0; ds<6; ds++)
        qf[ds] = *reinterpret_cast<const f16x8*>(Qh + (size_t)(qw + c)*192 + ds*32 + g*8);
    bool pm[4];
    for (int r=0;r<4;r++) pm[r] = am[b*2048 + qw + g*4 + r] != 0;

    f32x4 zero = {0.f,0.f,0.f,0.f};
    f32x4 acc[12];
    for (int i=0;i<12;i++) acc[i] = zero;

    const int kend = min(ch*256 + 256, qw + 16);
    for (int k0 = ch*256; k0 < kend; k0 += 64){
        for (int kt2=0; kt2<4; kt2++){
            int kk = k0 + kt2*16;
            f32x4 sacc = zero;
            for (int ds=0; ds<6; ds++){
                f16x8 kf = *reinterpret_cast<const f16x8*>(Kh + (size_t)(kk + c)*192 + ds*32 + g*8);
                sacc = MFMA16(qf[ds], kf, sacc);
            }
            float Mk = Mh[kk + c], iL = Lh[kk + c];
            for (int r=0;r<4;r++){
                int q = qw + g*4 + r;
                float v = sacc[r]*SC;
                if (pm[r]) v = NEGV;
                float p = __expf(v - Mk)*iL;
                if (kk + c > q) p = 0.f;      // causal (handles diag + overshoot)
                int row = g*4 + r;
                int byo = (row*128 + (kt2*16 + c)*2) ^ ((row&7)<<4);
                *reinterpret_cast<f16*>(Pb + byo) = (f16)p;
            }
        }
        for (int ks=0; ks<2; ks++){
            int byo = (c*128 + ks*64 + g*16) ^ ((c&7)<<4);
            f16x8 pa = *reinterpret_cast<const f16x8*>(Pb + byo);
            for (int dt=0; dt<12; dt++){
                f16x8 vb = *reinterpret_cast<const f16x8*>(Vh + (size_t)(dt*16 + c)*2048 + k0 + ks*32 + g*8);
                acc[dt] = MFMA16(pa, vb, acc[dt]);
            }
        }
    }
    for (int dt=0; dt<12; dt++){
        int d = h*192 + dt*16 + c;
        for (int r=0;r<4;r++){
            int q = qw + g*4 + r;
            atomicAdd(&x1[(size_t)(b*2048 + q)*768 + d], acc[dt][r]);
        }
    }
}

// ---------------- residual + layernorm ----------------
__global__ __launch_bounds__(256) void ln_kernel(
    const float* __restrict__ x, const float* __restrict__ x1,
    const float* __restrict__ gamma, const float* __restrict__ beta,
    float* __restrict__ out)
{
    const int r = blockIdx.x, t = threadIdx.x;
    const float* xr = x  + (size_t)r*768;
    const float* yr = x1 + (size_t)r*768;
    float v[3]; float s1 = 0.f, s2 = 0.f;
    for (int i=0;i<3;i++){ int j = t + i*256; float y = xr[j] + yr[j]; v[i]=y; s1+=y; s2+=y*y; }
    for (int o=32;o>=1;o>>=1){ s1 += __shfl_xor(s1,o); s2 += __shfl_xor(s2,o); }
    __shared__ float a1[4], a2[4];
    if ((t&63)==0){ a1[t>>6]=s1; a2[t>>6]=s2; }
    __syncthreads();
    s1 = a1[0]+a1[1]+a1[2]+a1[3];
    s2 = a2[0]+a2[1]+a2[2]+a2[3];
    float mu  = s1*(1.f/768.f);
    float var = s2*(1.f/768.f) - mu*mu;
    float rs  = rsqrtf(var + 1e-5f);
    for (int i=0;i<3;i++){
        int j = t + i*256;
        out[(size_t)r*768 + j] = (v[i]-mu)*rs*gamma[j] + beta[j];
    }
}

extern "C" void kernel_launch(void* const* d_in, const int* in_sizes, int n_in,
                              void* d_out, int out_size, void* d_ws, size_t ws_size,
                              hipStream_t stream)
{
    const float* x     = (const float*)d_in[0];
    const unsigned char* am = (const unsigned char*)d_in[1];
    const float* Wq    = (const float*)d_in[2];
    const float* bq    = (const float*)d_in[3];
    const float* Wk    = (const float*)d_in[4];
    const float* bk    = (const float*)d_in[5];
    const float* Wv    = (const float*)d_in[6];
    const float* bv    = (const float*)d_in[7];
    const float* gamma = (const float*)d_in[8];
    const float* beta  = (const float*)d_in[9];
    float* out = (float*)d_out;

    f16* xb  = (f16*)d_ws;
    f16* Wb  = xb + (size_t)8192*768;          // 3 weight matrices fp16
    f16* Qb  = Wb + (size_t)3*768*768;
    f16* Kb  = Qb + (size_t)16*2048*192;
    f16* Vt  = Kb + (size_t)16*2048*192;
    float* Mst = (float*)(Vt + (size_t)16*2048*192);
    float* Lst = Mst + 16*2048;
    float* x1  = Lst + 16*2048;
    // chunk partials alias xb (dead after proj_kernel)
    float* Mp  = (float*)xb;                   // 16*8*2048 floats
    float* Lp  = Mp + 16*8*2048;

    cvt_kernel<<<6144, 256, 0, stream>>>(x,  xb, 8192*768);
    cvt_kernel<<<576,  256, 0, stream>>>(Wq, Wb,            589824);
    cvt_kernel<<<576,  256, 0, stream>>>(Wk, Wb + 589824,   589824);
    cvt_kernel<<<576,  256, 0, stream>>>(Wv, Wb + 2*589824, 589824);
    proj_kernel<<<dim3(6,64,3), 256, 0, stream>>>(xb, Wb, bq, bk, bv, Qb, Kb, Vt);
    colstats_kernel<<<dim3(32,8,16), 256, 0, stream>>>(Qb, Kb, am, Mp, Lp);
    combine_kernel<<<128, 256, 0, stream>>>(Mp, Lp, Mst, Lst);
    zero_kernel<<<6144, 256, 0, stream>>>(x1, 8192*768);
    attn_kernel<<<dim3(32,8,16), 256, 0, stream>>>(Qb, Kb, Vt, Mst, Lst, am, x1);
    ln_kernel<<<8192, 256, 0, stream>>>(x, x1, gamma, beta, out);
}

// Round 6
// 375.719 us; speedup vs baseline: 2.0205x; 1.9375x over previous
//
#include <hip/hip_runtime.h>

typedef _Float16 f16;
typedef _Float16 f16x8 __attribute__((ext_vector_type(8)));
typedef _Float16 f16x4 __attribute__((ext_vector_type(4)));
typedef float    f32x4 __attribute__((ext_vector_type(4)));

#define MFMA16(a,b,c) __builtin_amdgcn_mfma_f32_16x16x32_f16(a,b,c,0,0,0)

static constexpr float NEGV = -1e9f;
static constexpr float SC   = 0.05f;   // 1/SCALE = 1/20

__device__ __forceinline__ void gload16(const void* g, void* l){
    __builtin_amdgcn_global_load_lds(
        (const __attribute__((address_space(1))) void*)g,
        (__attribute__((address_space(3))) void*)l, 16, 0, 0);
}

// ---------------- f32 -> f16 convert ----------------
__global__ __launch_bounds__(256) void cvt_kernel(const float* __restrict__ in,
                                                  f16* __restrict__ out, int n){
    int i = (blockIdx.x*256 + threadIdx.x)*4;
    if (i < n){
        float4 v = *reinterpret_cast<const float4*>(in + i);
        f16x4 o = { (f16)v.x, (f16)v.y, (f16)v.z, (f16)v.w };
        *reinterpret_cast<f16x4*>(out + i) = o;
    }
}

// ---------------- zero-init f32 buffer ----------------
__global__ __launch_bounds__(256) void zero_kernel(float* __restrict__ p, int n){
    int i = (blockIdx.x*256 + threadIdx.x)*4;
    if (i < n){
        float4 z = {0.f,0.f,0.f,0.f};
        *reinterpret_cast<float4*>(p + i) = z;
    }
}

// ---------------- QKV projection: C[m,n] = sum_k X[m,k]*W[n,k] + b[n] ----------------
// z=0 -> Q [bh][s][192], z=1 -> K [bh][s][192], z=2 -> V transposed [bh][192][s]
__global__ __launch_bounds__(256) void proj_kernel(
    const f16* __restrict__ xb, const f16* __restrict__ Wb,
    const float* __restrict__ bq, const float* __restrict__ bk, const float* __restrict__ bv,
    f16* __restrict__ Qb, f16* __restrict__ Kb, f16* __restrict__ Vt)
{
    __shared__ f16 As[128*32];
    __shared__ f16 Bs[128*32];
    const int z = blockIdx.z;
    const f16*   Wz   = Wb + (size_t)z*768*768;
    const float* bias = (z==0) ? bq : (z==1 ? bk : bv);
    f16*         out  = (z==0) ? Qb : (z==1 ? Kb : Vt);
    const int row0 = blockIdx.y*128, n0 = blockIdx.x*128;
    const int tid = threadIdx.x, w = tid>>6, l = tid&63;
    const int wm = w>>1, wn = w&1, c = l&15, g = l>>4;
    f32x4 zero = {0.f,0.f,0.f,0.f};
    f32x4 acc[4][4];
    for (int i=0;i<4;i++) for (int j=0;j<4;j++) acc[i][j] = zero;

    const f16* ag = xb + (size_t)(row0 + w*32 + (l>>2))*768 + (l&3)*8;
    const f16* bg = Wz + (size_t)(n0   + w*32 + (l>>2))*768 + (l&3)*8;
    f16* asd = As + w*1024;
    f16* bsd = Bs + w*1024;

    for (int k0 = 0; k0 < 768; k0 += 32){
        __syncthreads();
        gload16(ag + k0,          asd      );
        gload16(ag + k0 + 16*768, asd + 512);
        gload16(bg + k0,          bsd      );
        gload16(bg + k0 + 16*768, bsd + 512);
        __syncthreads();
        f16x8 af[4], bf[4];
        for (int mt=0; mt<4; mt++)
            af[mt] = *reinterpret_cast<const f16x8*>(As + (wm*64 + mt*16 + c)*32 + g*8);
        for (int nt=0; nt<4; nt++)
            bf[nt] = *reinterpret_cast<const f16x8*>(Bs + (wn*64 + nt*16 + c)*32 + g*8);
        for (int mt=0; mt<4; mt++)
            for (int nt=0; nt<4; nt++)
                acc[mt][nt] = MFMA16(af[mt], bf[nt], acc[mt][nt]);
    }

    for (int nt=0; nt<4; nt++){
        int nb = n0 + wn*64 + nt*16;
        int h  = nb/192;
        int d  = (nb - h*192) + c;
        float bv_ = bias[nb + c];
        for (int mt=0; mt<4; mt++){
            int mb = row0 + wm*64 + mt*16 + g*4;
            if (z < 2){
                for (int r=0;r<4;r++){
                    int m = mb + r; int bi = m>>11, s = m&2047;
                    out[(size_t)((bi*4 + h)*2048 + s)*192 + d] = (f16)(acc[mt][nt][r] + bv_);
                }
            } else {
                int bi = mb>>11, s0 = mb&2047;
                f16x4 pk = { (f16)(acc[mt][nt][0] + bv_), (f16)(acc[mt][nt][1] + bv_),
                             (f16)(acc[mt][nt][2] + bv_), (f16)(acc[mt][nt][3] + bv_) };
                *reinterpret_cast<f16x4*>(&out[(size_t)((bi*4 + h)*192 + d)*2048 + s0]) = pk;
            }
        }
    }
}

// ---------------- pass 1: per-column (k) partial softmax stats over a q-chunk ----------------
// grid (kb=16 [128 k-cols], ch=4 [512 q], bh=16), 512 threads (8 waves).
// Q-tiles staged in LDS fragment-major, shared by all 8 waves. K-frags in registers.
// NOTE: no early return — every block MUST write its (M,L) partial, else combine
// reads poisoned/aliased memory (R4 bug: absmax 5.9 from garbage partials).
__global__ __launch_bounds__(512) void colstats_kernel(
    const f16* __restrict__ Qb, const f16* __restrict__ Kb,
    const unsigned char* __restrict__ am,
    float* __restrict__ Mp, float* __restrict__ Lp)
{
    __shared__ f16 Qf[64*192];   // 24KB, fragment-major: chunk(j2*6+ds)*512 f16, slot (g*16+c)*8
    const int bh = blockIdx.z, b = bh>>2;
    const int ch = blockIdx.y;
    const int kb = blockIdx.x;
    const int tid = threadIdx.x, w = tid>>6, l = tid&63;
    const int c = l&15, g = l>>4;
    const int kt = kb*128 + w*16;
    const f16* Qh = Qb + (size_t)bh*2048*192;
    const f16* Kh = Kb + (size_t)bh*2048*192;
    const unsigned char* amb = am + b*2048;

    f16x8 kf[6];
    for (int ds=0; ds<6; ds++)
        kf[ds] = *reinterpret_cast<const f16x8*>(Kh + (size_t)(kt + c)*192 + ds*32 + g*8);

    // staging chunk ids for this wave: w*3 .. w*3+2
    int cid[3], cj2[3], cds[3];
    for (int i=0;i<3;i++){ cid[i] = w*3+i; cj2[i] = cid[i]/6; cds[i] = cid[i]-cj2[i]*6; }

    float M = -1e38f, L = 0.f;
    f32x4 zero = {0.f,0.f,0.f,0.f};
    const int qt0 = max(ch*512, kb*128);   // if qt0 >= qt1 the loop is empty -> neutral (M,L)
    const int qt1 = ch*512 + 512;

    for (int qt = qt0; qt < qt1; qt += 64){
        __syncthreads();
        for (int i=0;i<3;i++)
            gload16(Qh + (size_t)(qt + cj2[i]*16 + c)*192 + cds[i]*32 + g*8,
                    Qf + cid[i]*512);
        __syncthreads();   // drains vmcnt(0) + barrier

        for (int j2=0; j2<4; j2++){
            int q0 = qt + j2*16;
            if (q0 + 15 < kt) continue;          // tile fully above diagonal for this wave
            f32x4 sacc = zero;
            for (int ds=0; ds<6; ds++){
                f16x8 qfr = *reinterpret_cast<const f16x8*>(Qf + ((j2*6+ds)*64 + g*16 + c)*8);
                sacc = MFMA16(qfr, kf[ds], sacc);
            }
            float sv[4]; float m4 = -1e38f;
            for (int r=0;r<4;r++){
                int q = q0 + g*4 + r;
                float v = sacc[r]*SC;
                if (amb[q]) v = NEGV;
                if (q < kt + c) v = -1e38f;      // causal-invalid: contributes 0
                sv[r] = v; m4 = fmaxf(m4, v);
            }
            m4 = fmaxf(m4, __shfl_xor(m4, 16));
            m4 = fmaxf(m4, __shfl_xor(m4, 32));
            float Mn = fmaxf(M, m4);
            float p = __expf(sv[0]-Mn) + __expf(sv[1]-Mn) + __expf(sv[2]-Mn) + __expf(sv[3]-Mn);
            p += __shfl_xor(p, 16);
            p += __shfl_xor(p, 32);
            L = L*__expf(M - Mn) + p;
            M = Mn;
        }
    }
    if (l < 16){
        size_t o = ((size_t)bh*4 + ch)*2048 + kt + l;
        Mp[o] = M;
        Lp[o] = L;
    }
}

// ---------------- combine chunk partials -> M, 1/L ----------------
__global__ __launch_bounds__(256) void combine_kernel(
    const float* __restrict__ Mp, const float* __restrict__ Lp,
    float* __restrict__ Mst, float* __restrict__ Lst)
{
    int idx = blockIdx.x*256 + threadIdx.x;   // 16*2048
    int bh = idx >> 11, col = idx & 2047;
    float m[4];
    float M = -1e38f;
    for (int ch=0; ch<4; ch++){
        m[ch] = Mp[((size_t)bh*4 + ch)*2048 + col];
        M = fmaxf(M, m[ch]);
    }
    float L = 0.f;
    for (int ch=0; ch<4; ch++)
        L += Lp[((size_t)bh*4 + ch)*2048 + col] * __expf(m[ch] - M);
    Mst[(size_t)bh*2048 + col] = M;
    Lst[(size_t)bh*2048 + col] = 1.f/L;
}

// ---------------- pass 2: x1[q,:] += sum_{k in chunk, k<=q} exp(s-M[k])*invL[k] * V[k,:] ----------------
// grid (qb=16 [128 q-rows], ch=4 [512 k], bh=16), 512 threads (8 waves).
// K and V tiles staged in LDS fragment-major via global_load_lds, shared by 8 waves.
__global__ __launch_bounds__(512) void attn_kernel(
    const f16* __restrict__ Qb, const f16* __restrict__ Kb, const f16* __restrict__ Vt,
    const float* __restrict__ Mst, const float* __restrict__ Lst,
    const unsigned char* __restrict__ am,
    float* __restrict__ x1)
{
    __shared__ f16 Kf[64*192];   // 24KB: chunk(kt2*6+ds)*512, slot (g*16+c)*8
    __shared__ f16 Vf[192*64];   // 24KB: chunk(dt*2+ks)*512, slot (g*16+c)*8
    __shared__ f16 Pl[8*1024];   // per-wave 16x64 fp16, XOR-swizzled (2KB each)
    const int bh = blockIdx.z, b = bh>>2, h = bh&3;
    const int qb = blockIdx.x;
    const int ch = blockIdx.y;
    if (qb < 4*ch) return;                    // block-uniform: contributes nothing (atomic accum)
    const int tid = threadIdx.x, w = tid>>6, l = tid&63;
    const int c = l&15, g = l>>4;
    const int qw = qb*128 + w*16;
    const f16* Qh = Qb + (size_t)bh*2048*192;
    const f16* Kh = Kb + (size_t)bh*2048*192;
    const f16* Vh = Vt + (size_t)bh*192*2048;
    const float* Mh = Mst + (size_t)bh*2048;
    const float* Lh = Lst + (size_t)bh*2048;
    char* Pb = (char*)(Pl + w*1024);

    f16x8 qf[6];
    for (int ds=0; ds<6; ds++)
        qf[ds] = *reinterpret_cast<const f16x8*>(Qh + (size_t)(qw + c)*192 + ds*32 + g*8);
    bool pm[4];
    for (int r=0;r<4;r++) pm[r] = am[b*2048 + qw + g*4 + r] != 0;

    // staging chunk ids: K chunks w*3..w*3+2 (kt2=cid/6, ds=cid%6); V same ids (dt=cid/2, ks=cid%2)
    int cid[3], kt2s[3], dss[3], dts[3], kss[3];
    for (int i=0;i<3;i++){
        cid[i] = w*3+i;
        kt2s[i] = cid[i]/6; dss[i] = cid[i]-kt2s[i]*6;
        dts[i]  = cid[i]>>1; kss[i] = cid[i]&1;
    }

    f32x4 zero = {0.f,0.f,0.f,0.f};
    f32x4 acc[12];
    for (int i=0;i<12;i++) acc[i] = zero;

    const int kend = min(ch*512 + 512, qb*128 + 128);
    for (int k0 = ch*512; k0 < kend; k0 += 64){
        __syncthreads();
        for (int i=0;i<3;i++){
            gload16(Kh + (size_t)(k0 + kt2s[i]*16 + c)*192 + dss[i]*32 + g*8,
                    Kf + cid[i]*512);
            gload16(Vh + (size_t)(dts[i]*16 + c)*2048 + k0 + kss[i]*32 + g*8,
                    Vf + cid[i]*512);
        }
        __syncthreads();   // drains vmcnt(0) + barrier

        if (k0 <= qw + 15){
            for (int kt2=0; kt2<4; kt2++){
                int kk = k0 + kt2*16;
                f32x4 sacc = zero;
                for (int ds=0; ds<6; ds++){
                    f16x8 kfr = *reinterpret_cast<const f16x8*>(Kf + ((kt2*6+ds)*64 + g*16 + c)*8);
                    sacc = MFMA16(qf[ds], kfr, sacc);
                }
                float Mk = Mh[kk + c], iL = Lh[kk + c];
                for (int r=0;r<4;r++){
                    int q = qw + g*4 + r;
                    float v = sacc[r]*SC;
                    if (pm[r]) v = NEGV;
                    float p = __expf(v - Mk)*iL;
                    if (kk + c > q) p = 0.f;      // causal
                    int row = g*4 + r;
                    int byo = (row*128 + (kt2*16 + c)*2) ^ ((row&7)<<4);
                    *reinterpret_cast<f16*>(Pb + byo) = (f16)p;
                }
            }
            for (int ks=0; ks<2; ks++){
                int byo = (c*128 + ks*64 + g*16) ^ ((c&7)<<4);
                f16x8 pa = *reinterpret_cast<const f16x8*>(Pb + byo);
                for (int dt=0; dt<12; dt++){
                    f16x8 vb = *reinterpret_cast<const f16x8*>(Vf + ((dt*2+ks)*64 + g*16 + c)*8);
                    acc[dt] = MFMA16(pa, vb, acc[dt]);
                }
            }
        }
    }
    for (int dt=0; dt<12; dt++){
        int d = h*192 + dt*16 + c;
        for (int r=0;r<4;r++){
            int q = qw + g*4 + r;
            atomicAdd(&x1[(size_t)(b*2048 + q)*768 + d], acc[dt][r]);
        }
    }
}

// ---------------- residual + layernorm ----------------
__global__ __launch_bounds__(256) void ln_kernel(
    const float* __restrict__ x, const float* __restrict__ x1,
    const float* __restrict__ gamma, const float* __restrict__ beta,
    float* __restrict__ out)
{
    const int r = blockIdx.x, t = threadIdx.x;
    const float* xr = x  + (size_t)r*768;
    const float* yr = x1 + (size_t)r*768;
    float v[3]; float s1 = 0.f, s2 = 0.f;
    for (int i=0;i<3;i++){ int j = t + i*256; float y = xr[j] + yr[j]; v[i]=y; s1+=y; s2+=y*y; }
    for (int o=32;o>=1;o>>=1){ s1 += __shfl_xor(s1,o); s2 += __shfl_xor(s2,o); }
    __shared__ float a1[4], a2[4];
    if ((t&63)==0){ a1[t>>6]=s1; a2[t>>6]=s2; }
    __syncthreads();
    s1 = a1[0]+a1[1]+a1[2]+a1[3];
    s2 = a2[0]+a2[1]+a2[2]+a2[3];
    float mu  = s1*(1.f/768.f);
    float var = s2*(1.f/768.f) - mu*mu;
    float rs  = rsqrtf(var + 1e-5f);
    for (int i=0;i<3;i++){
        int j = t + i*256;
        out[(size_t)r*768 + j] = (v[i]-mu)*rs*gamma[j] + beta[j];
    }
}

extern "C" void kernel_launch(void* const* d_in, const int* in_sizes, int n_in,
                              void* d_out, int out_size, void* d_ws, size_t ws_size,
                              hipStream_t stream)
{
    const float* x     = (const float*)d_in[0];
    const unsigned char* am = (const unsigned char*)d_in[1];
    const float* Wq    = (const float*)d_in[2];
    const float* bq    = (const float*)d_in[3];
    const float* Wk    = (const float*)d_in[4];
    const float* bk    = (const float*)d_in[5];
    const float* Wv    = (const float*)d_in[6];
    const float* bv    = (const float*)d_in[7];
    const float* gamma = (const float*)d_in[8];
    const float* beta  = (const float*)d_in[9];
    float* out = (float*)d_out;

    f16* xb  = (f16*)d_ws;
    f16* Wb  = xb + (size_t)8192*768;          // 3 weight matrices fp16
    f16* Qb  = Wb + (size_t)3*768*768;
    f16* Kb  = Qb + (size_t)16*2048*192;
    f16* Vt  = Kb + (size_t)16*2048*192;
    float* Mst = (float*)(Vt + (size_t)16*2048*192);
    float* Lst = Mst + 16*2048;
    float* x1  = Lst + 16*2048;
    // chunk partials alias xb (dead after proj_kernel; every slot IS written by colstats)
    float* Mp  = (float*)xb;                   // 16*4*2048 floats
    float* Lp  = Mp + 16*4*2048;

    cvt_kernel<<<6144, 256, 0, stream>>>(x,  xb, 8192*768);
    cvt_kernel<<<576,  256, 0, stream>>>(Wq, Wb,            589824);
    cvt_kernel<<<576,  256, 0, stream>>>(Wk, Wb + 589824,   589824);
    cvt_kernel<<<576,  256, 0, stream>>>(Wv, Wb + 2*589824, 589824);
    proj_kernel<<<dim3(6,64,3), 256, 0, stream>>>(xb, Wb, bq, bk, bv, Qb, Kb, Vt);
    colstats_kernel<<<dim3(16,4,16), 512, 0, stream>>>(Qb, Kb, am, Mp, Lp);
    combine_kernel<<<128, 256, 0, stream>>>(Mp, Lp, Mst, Lst);
    zero_kernel<<<6144, 256, 0, stream>>>(x1, 8192*768);
    attn_kernel<<<dim3(16,4,16), 512, 0, stream>>>(Qb, Kb, Vt, Mst, Lst, am, x1);
    ln_kernel<<<8192, 256, 0, stream>>>(x, x1, gamma, beta, out);
}

// Round 7
// 304.116 us; speedup vs baseline: 2.4962x; 1.2354x over previous
//
#include <hip/hip_runtime.h>

typedef _Float16 f16;
typedef _Float16 f16x8 __attribute__((ext_vector_type(8)));
typedef _Float16 f16x4 __attribute__((ext_vector_type(4)));
typedef float    f32x4 __attribute__((ext_vector_type(4)));

#define MFMA16(a,b,c) __builtin_amdgcn_mfma_f32_16x16x32_f16(a,b,c,0,0,0)

static constexpr float NEGV = -1e9f;
static constexpr float SC   = 0.05f;   // 1/SCALE = 1/20

// Fragment-major layouts (written by proj, consumed by colstats/attn):
//  Q,K:  [bh][tile16 t][ds 0..5][slot 0..63][e 0..7]   slot=(g*16+c) <-> row=t*16+c, col=ds*32+g*8+e
//  V:    [bh][kb64][cid 0..23][slot][e]  cid=dt*2+ks  <-> d=dt*16+c,  k=kb64*64+ks*32+g*8+e

__device__ __forceinline__ void gload16(const void* g, void* l){
    __builtin_amdgcn_global_load_lds(
        (const __attribute__((address_space(1))) void*)g,
        (__attribute__((address_space(3))) void*)l, 16, 0, 0);
}

// ---------------- f32 -> f16 convert ----------------
__global__ __launch_bounds__(256) void cvt_kernel(const float* __restrict__ in,
                                                  f16* __restrict__ out, int n){
    int i = (blockIdx.x*256 + threadIdx.x)*4;
    if (i < n){
        float4 v = *reinterpret_cast<const float4*>(in + i);
        f16x4 o = { (f16)v.x, (f16)v.y, (f16)v.z, (f16)v.w };
        *reinterpret_cast<f16x4*>(out + i) = o;
    }
}

// ---------------- zero-init f32 buffer ----------------
__global__ __launch_bounds__(256) void zero_kernel(float* __restrict__ p, int n){
    int i = (blockIdx.x*256 + threadIdx.x)*4;
    if (i < n){
        float4 z = {0.f,0.f,0.f,0.f};
        *reinterpret_cast<float4*>(p + i) = z;
    }
}

// ---------------- QKV projection ----------------
__global__ __launch_bounds__(256) void proj_kernel(
    const f16* __restrict__ xb, const f16* __restrict__ Wb,
    const float* __restrict__ bq, const float* __restrict__ bk, const float* __restrict__ bv,
    f16* __restrict__ Qb, f16* __restrict__ Kb, f16* __restrict__ Vt)
{
    __shared__ f16 As[128*32];
    __shared__ f16 Bs[128*32];
    const int z = blockIdx.z;
    const f16*   Wz   = Wb + (size_t)z*768*768;
    const float* bias = (z==0) ? bq : (z==1 ? bk : bv);
    f16*         out  = (z==0) ? Qb : (z==1 ? Kb : Vt);
    const int row0 = blockIdx.y*128, n0 = blockIdx.x*128;
    const int tid = threadIdx.x, w = tid>>6, l = tid&63;
    const int wm = w>>1, wn = w&1, c = l&15, g = l>>4;
    f32x4 zero = {0.f,0.f,0.f,0.f};
    f32x4 acc[4][4];
    for (int i=0;i<4;i++) for (int j=0;j<4;j++) acc[i][j] = zero;

    const f16* ag = xb + (size_t)(row0 + w*32 + (l>>2))*768 + (l&3)*8;
    const f16* bg = Wz + (size_t)(n0   + w*32 + (l>>2))*768 + (l&3)*8;
    f16* asd = As + w*1024;
    f16* bsd = Bs + w*1024;

    for (int k0 = 0; k0 < 768; k0 += 32){
        __syncthreads();
        gload16(ag + k0,          asd      );
        gload16(ag + k0 + 16*768, asd + 512);
        gload16(bg + k0,          bsd      );
        gload16(bg + k0 + 16*768, bsd + 512);
        __syncthreads();
        f16x8 af[4], bf[4];
        for (int mt=0; mt<4; mt++)
            af[mt] = *reinterpret_cast<const f16x8*>(As + (wm*64 + mt*16 + c)*32 + g*8);
        for (int nt=0; nt<4; nt++)
            bf[nt] = *reinterpret_cast<const f16x8*>(Bs + (wn*64 + nt*16 + c)*32 + g*8);
        for (int mt=0; mt<4; mt++)
            for (int nt=0; nt<4; nt++)
                acc[mt][nt] = MFMA16(af[mt], bf[nt], acc[mt][nt]);
    }

    for (int nt=0; nt<4; nt++){
        int nb = n0 + wn*64 + nt*16;
        int h  = nb/192;
        int d  = (nb - h*192) + c;            // head-dim col/row, fixed per (nt, lane)
        float bv_ = bias[nb + c];
        for (int mt=0; mt<4; mt++){
            int mb = row0 + wm*64 + mt*16 + g*4;
            int bi = mb>>11, s0 = mb&2047;
            int bh = bi*4 + h;
            if (z < 2){
                int ds = d>>5, gg = (d>>3)&3, e = d&7;
                for (int r=0;r<4;r++){
                    int s = s0 + r;
                    out[ ((size_t)(bh*128 + (s>>4))*6 + ds)*512 + ((gg*16) + (s&15))*8 + e ]
                        = (f16)(acc[mt][nt][r] + bv_);
                }
            } else {
                int dt = d>>4, cV = d&15;
                int kb64 = s0>>6, ks = (s0>>5)&1, gk = (s0>>3)&3, e0 = s0&7;
                f16x4 pk = { (f16)(acc[mt][nt][0] + bv_), (f16)(acc[mt][nt][1] + bv_),
                             (f16)(acc[mt][nt][2] + bv_), (f16)(acc[mt][nt][3] + bv_) };
                *reinterpret_cast<f16x4*>(
                    &out[ ((size_t)(bh*32 + kb64)*24 + dt*2 + ks)*512 + (gk*16 + cV)*8 + e0 ]) = pk;
            }
        }
    }
}

// ---------------- pass 1: per-column (k) partial softmax stats over a q-chunk ----------------
// grid (kb=16 [128 k-cols], ch=4 [512 q], bh=16), 512 threads (8 waves).
// Q-tiles (64 rows, frag-major, contiguous 24KB) double-buffer staged; K-frags in regs.
// Every block writes its (M,L) partial (no early return — R4 lesson).
__global__ __launch_bounds__(512,4) void colstats_kernel(
    const f16* __restrict__ Qb, const f16* __restrict__ Kb,
    const unsigned char* __restrict__ am,
    float* __restrict__ Mp, float* __restrict__ Lp)
{
    __shared__ f16 Qs[2][24*512];   // 2 x 24KB
    const int bh = blockIdx.z, b = bh>>2;
    const int ch = blockIdx.y;
    const int kb = blockIdx.x;
    const int tid = threadIdx.x, w = tid>>6, l = tid&63;
    const int c = l&15, g = l>>4;
    const int kt = kb*128 + w*16;
    const f16* Qfm = Qb + (size_t)bh*128*6*512;
    const unsigned char* amb = am + b*2048;

    f16x8 kf[6];
    {
        const f16* kbase = Kb + ((size_t)(bh*128 + kb*8 + w)*6)*512 + l*8;
        for (int ds=0; ds<6; ds++) kf[ds] = *reinterpret_cast<const f16x8*>(kbase + ds*512);
    }

    float M = -1e38f, L = 0.f;
    f32x4 zero = {0.f,0.f,0.f,0.f};
    const int qt0 = max(ch*512, kb*128);
    const int qt1 = ch*512 + 512;
    const int nt  = (qt1 - qt0) >> 6;      // 64-row q-tiles (block-uniform)

    if (nt > 0){
        const int cid = w*3;   // this wave stages chunks cid..cid+2
        // prologue
        {
            const f16* src = Qfm + ((size_t)(qt0>>4)*6 + cid)*512 + l*8;
            gload16(src,        &Qs[0][cid*512]);
            gload16(src + 512,  &Qs[0][(cid+1)*512]);
            gload16(src + 1024, &Qs[0][(cid+2)*512]);
        }
        __syncthreads();
        for (int it=0; it<nt; it++){
            int cur = it&1;
            if (it+1 < nt){
                const f16* src = Qfm + ((size_t)((qt0 + (it+1)*64)>>4)*6 + cid)*512 + l*8;
                gload16(src,        &Qs[cur^1][cid*512]);
                gload16(src + 512,  &Qs[cur^1][(cid+1)*512]);
                gload16(src + 1024, &Qs[cur^1][(cid+2)*512]);
            }
            int qt = qt0 + it*64;
            for (int j2=0; j2<4; j2++){
                int q0 = qt + j2*16;
                if (q0 + 15 < kt) continue;
                f32x4 sacc = zero;
                for (int ds=0; ds<6; ds++){
                    f16x8 qfr = *reinterpret_cast<const f16x8*>(&Qs[cur][(j2*6+ds)*512 + l*8]);
                    sacc = MFMA16(qfr, kf[ds], sacc);
                }
                float sv[4]; float m4 = -1e38f;
                for (int r=0;r<4;r++){
                    int q = q0 + g*4 + r;
                    float v = sacc[r]*SC;
                    if (amb[q]) v = NEGV;
                    if (q < kt + c) v = -1e38f;
                    sv[r] = v; m4 = fmaxf(m4, v);
                }
                m4 = fmaxf(m4, __shfl_xor(m4, 16));
                m4 = fmaxf(m4, __shfl_xor(m4, 32));
                float Mn = fmaxf(M, m4);
                float p = __expf(sv[0]-Mn) + __expf(sv[1]-Mn) + __expf(sv[2]-Mn) + __expf(sv[3]-Mn);
                p += __shfl_xor(p, 16);
                p += __shfl_xor(p, 32);
                L = L*__expf(M - Mn) + p;
                M = Mn;
            }
            __syncthreads();
        }
    }
    if (l < 16){
        size_t o = ((size_t)bh*4 + ch)*2048 + kt + l;
        Mp[o] = M;
        Lp[o] = L;
    }
}

// ---------------- combine chunk partials -> M, 1/L ----------------
__global__ __launch_bounds__(256) void combine_kernel(
    const float* __restrict__ Mp, const float* __restrict__ Lp,
    float* __restrict__ Mst, float* __restrict__ Lst)
{
    int idx = blockIdx.x*256 + threadIdx.x;   // 16*2048
    int bh = idx >> 11, col = idx & 2047;
    float m[4];
    float M = -1e38f;
    for (int ch=0; ch<4; ch++){
        m[ch] = Mp[((size_t)bh*4 + ch)*2048 + col];
        M = fmaxf(M, m[ch]);
    }
    float L = 0.f;
    for (int ch=0; ch<4; ch++)
        L += Lp[((size_t)bh*4 + ch)*2048 + col] * __expf(m[ch] - M);
    Mst[(size_t)bh*2048 + col] = M;
    Lst[(size_t)bh*2048 + col] = 1.f/L;
}

// ---------------- pass 2: x1[q,:] += sum_{k in chunk, k<=q} exp(s-M[k])*invL[k] * V[k,:] ----------------
// grid (qb=16 [128 q-rows], ch=4 [512 k], bh=16), 512 threads (8 waves).
// K (2 tile16) + V (12 chunks) per 32-k step, frag-major contiguous chunks,
// double-buffered, stage issued BEFORE compute, one barrier per iter.
__global__ __launch_bounds__(512,4) void attn_kernel(
    const f16* __restrict__ Qb, const f16* __restrict__ Kb, const f16* __restrict__ Vt,
    const float* __restrict__ Mst, const float* __restrict__ Lst,
    const unsigned char* __restrict__ am,
    float* __restrict__ x1)
{
    __shared__ f16 Ks[2][12*512];    // 2 x 12KB
    __shared__ f16 Vs[2][12*512];    // 2 x 12KB
    __shared__ f16 Pl[8][16*32];     // 8 x 1KB, XOR-swizzled
    const int bh = blockIdx.z, b = bh>>2, h = bh&3;
    const int qb = blockIdx.x;
    const int ch = blockIdx.y;
    if (qb < 4*ch) return;
    const int tid = threadIdx.x, w = tid>>6, l = tid&63;
    const int c = l&15, g = l>>4;
    const int qw = qb*128 + w*16;
    const f16* Kfm = Kb + (size_t)bh*128*6*512;
    const f16* Vfm = Vt + (size_t)bh*32*24*512;
    const float* Mh = Mst + (size_t)bh*2048;
    const float* Lh = Lst + (size_t)bh*2048;
    char* Pb = (char*)(&Pl[w][0]);

    f16x8 qf[6];
    {
        const f16* qbase = Qb + ((size_t)(bh*128 + (qw>>4))*6)*512 + l*8;
        for (int ds=0; ds<6; ds++) qf[ds] = *reinterpret_cast<const f16x8*>(qbase + ds*512);
    }
    bool pm[4];
    for (int r=0;r<4;r++) pm[r] = am[b*2048 + qw + g*4 + r] != 0;

    f32x4 zero = {0.f,0.f,0.f,0.f};
    f32x4 acc[12];
    for (int i=0;i<12;i++) acc[i] = zero;

    const int k00  = ch*512;
    const int kend = min(ch*512 + 512, qb*128 + 128);
    const int nt   = (kend - k00) >> 5;    // 32-k steps

    // staging assignment: wave w stages chunks w*3..w*3+2 of 24 (12 K + 12 V)
    const int cid = w*3;

    auto stage = [&](int buf, int k0){
        for (int i=0;i<3;i++){
            int ci = cid + i;
            if (ci < 12){
                // K chunk: tile (k0>>4)+tl, frag ds
                int tl = ci/6, ds = ci - tl*6;
                gload16(Kfm + ((size_t)((k0>>4) + tl)*6 + ds)*512 + l*8, &Ks[buf][ci*512]);
            } else {
                // V chunk dt
                int dt = ci - 12;
                int ks = (k0>>5)&1;
                gload16(Vfm + ((size_t)(k0>>6)*24 + dt*2 + ks)*512 + l*8, &Vs[buf][dt*512]);
            }
        }
    };

    stage(0, k00);
    __syncthreads();
    for (int it=0; it<nt; it++){
        int cur = it&1;
        int k0  = k00 + it*32;
        if (it+1 < nt) stage(cur^1, k0 + 32);

        if (k0 <= qw + 15){
            for (int kt2=0; kt2<2; kt2++){
                int kk = k0 + kt2*16;
                f32x4 sacc = zero;
                for (int ds=0; ds<6; ds++){
                    f16x8 kfr = *reinterpret_cast<const f16x8*>(&Ks[cur][(kt2*6+ds)*512 + l*8]);
                    sacc = MFMA16(qf[ds], kfr, sacc);
                }
                float Mk = Mh[kk + c], iL = Lh[kk + c];
                for (int r=0;r<4;r++){
                    int q = qw + g*4 + r;
                    float v = sacc[r]*SC;
                    if (pm[r]) v = NEGV;
                    float p = __expf(v - Mk)*iL;
                    if (kk + c > q) p = 0.f;
                    int row = g*4 + r;
                    int byo = (row*64 + (kt2*16 + c)*2) ^ ((row&3)<<4);
                    *reinterpret_cast<f16*>(Pb + byo) = (f16)p;
                }
            }
            {
                int byo = (c*64 + g*16) ^ ((c&3)<<4);
                f16x8 pa = *reinterpret_cast<const f16x8*>(Pb + byo);
                for (int dt=0; dt<12; dt++){
                    f16x8 vb = *reinterpret_cast<const f16x8*>(&Vs[cur][dt*512 + l*8]);
                    acc[dt] = MFMA16(pa, vb, acc[dt]);
                }
            }
        }
        __syncthreads();
    }
    for (int dt=0; dt<12; dt++){
        int d = h*192 + dt*16 + c;
        for (int r=0;r<4;r++){
            int q = qw + g*4 + r;
            atomicAdd(&x1[(size_t)(b*2048 + q)*768 + d], acc[dt][r]);
        }
    }
}

// ---------------- residual + layernorm ----------------
__global__ __launch_bounds__(256) void ln_kernel(
    const float* __restrict__ x, const float* __restrict__ x1,
    const float* __restrict__ gamma, const float* __restrict__ beta,
    float* __restrict__ out)
{
    const int r = blockIdx.x, t = threadIdx.x;
    const float* xr = x  + (size_t)r*768;
    const float* yr = x1 + (size_t)r*768;
    float v[3]; float s1 = 0.f, s2 = 0.f;
    for (int i=0;i<3;i++){ int j = t + i*256; float y = xr[j] + yr[j]; v[i]=y; s1+=y; s2+=y*y; }
    for (int o=32;o>=1;o>>=1){ s1 += __shfl_xor(s1,o); s2 += __shfl_xor(s2,o); }
    __shared__ float a1[4], a2[4];
    if ((t&63)==0){ a1[t>>6]=s1; a2[t>>6]=s2; }
    __syncthreads();
    s1 = a1[0]+a1[1]+a1[2]+a1[3];
    s2 = a2[0]+a2[1]+a2[2]+a2[3];
    float mu  = s1*(1.f/768.f);
    float var = s2*(1.f/768.f) - mu*mu;
    float rs  = rsqrtf(var + 1e-5f);
    for (int i=0;i<3;i++){
        int j = t + i*256;
        out[(size_t)r*768 + j] = (v[i]-mu)*rs*gamma[j] + beta[j];
    }
}

extern "C" void kernel_launch(void* const* d_in, const int* in_sizes, int n_in,
                              void* d_out, int out_size, void* d_ws, size_t ws_size,
                              hipStream_t stream)
{
    const float* x     = (const float*)d_in[0];
    const unsigned char* am = (const unsigned char*)d_in[1];
    const float* Wq    = (const float*)d_in[2];
    const float* bq    = (const float*)d_in[3];
    const float* Wk    = (const float*)d_in[4];
    const float* bk    = (const float*)d_in[5];
    const float* Wv    = (const float*)d_in[6];
    const float* bv    = (const float*)d_in[7];
    const float* gamma = (const float*)d_in[8];
    const float* beta  = (const float*)d_in[9];
    float* out = (float*)d_out;

    f16* xb  = (f16*)d_ws;
    f16* Wb  = xb + (size_t)8192*768;          // 3 weight matrices fp16
    f16* Qb  = Wb + (size_t)3*768*768;
    f16* Kb  = Qb + (size_t)16*2048*192;
    f16* Vt  = Kb + (size_t)16*2048*192;
    float* Mst = (float*)(Vt + (size_t)16*2048*192);
    float* Lst = Mst + 16*2048;
    float* x1  = Lst + 16*2048;
    // chunk partials alias xb (dead after proj_kernel; every slot IS written by colstats)
    float* Mp  = (float*)xb;                   // 16*4*2048 floats
    float* Lp  = Mp + 16*4*2048;

    cvt_kernel<<<6144, 256, 0, stream>>>(x,  xb, 8192*768);
    cvt_kernel<<<576,  256, 0, stream>>>(Wq, Wb,            589824);
    cvt_kernel<<<576,  256, 0, stream>>>(Wk, Wb + 589824,   589824);
    cvt_kernel<<<576,  256, 0, stream>>>(Wv, Wb + 2*589824, 589824);
    proj_kernel<<<dim3(6,64,3), 256, 0, stream>>>(xb, Wb, bq, bk, bv, Qb, Kb, Vt);
    colstats_kernel<<<dim3(16,4,16), 512, 0, stream>>>(Qb, Kb, am, Mp, Lp);
    combine_kernel<<<128, 256, 0, stream>>>(Mp, Lp, Mst, Lst);
    zero_kernel<<<6144, 256, 0, stream>>>(x1, 8192*768);
    attn_kernel<<<dim3(16,4,16), 512, 0, stream>>>(Qb, Kb, Vt, Mst, Lst, am, x1);
    ln_kernel<<<8192, 256, 0, stream>>>(x, x1, gamma, beta, out);
}

// Round 8
// 288.879 us; speedup vs baseline: 2.6279x; 1.0527x over previous
//
#include <hip/hip_runtime.h>

typedef _Float16 f16;
typedef _Float16 f16x8 __attribute__((ext_vector_type(8)));
typedef _Float16 f16x4 __attribute__((ext_vector_type(4)));
typedef float    f32x4 __attribute__((ext_vector_type(4)));

#define MFMA16(a,b,c) __builtin_amdgcn_mfma_f32_16x16x32_f16(a,b,c,0,0,0)

static constexpr float NEGV = -1e9f;
static constexpr float SC   = 0.05f;   // 1/SCALE = 1/20

// Fragment-major layouts (written by proj):
//  Q,K:  [bh][tile16 t][ds 0..5][slot 0..63][e 0..7]   slot=(g*16+c) <-> row=t*16+c, col=ds*32+g*8+e
//  V:    [bh][kb64][cid 0..23][slot][e]  cid=dt*2+ks  <-> d=dt*16+c,  k=kb64*64+ks*32+g*8+e
//  P:    [bh][poff(qt)+kc][slot 0..63][e 0..7]  A-frag: slot=(g*16+c) <-> q=qt*16+c, k=kc*32+g*8+e
//        triangular packed: kc = 0..qt>>1 ; poff(qt) = #chunks before qt ; 4160 chunks/bh

__device__ __forceinline__ int poff(int qt){
    int m = qt>>1;
    return qt + m*(m-1) + ((qt&1) ? m : 0);
}

__device__ __forceinline__ void gload16(const void* g, void* l){
    __builtin_amdgcn_global_load_lds(
        (const __attribute__((address_space(1))) void*)g,
        (__attribute__((address_space(3))) void*)l, 16, 0, 0);
}

// ---------------- f32 -> f16 convert ----------------
__global__ __launch_bounds__(256) void cvt_kernel(const float* __restrict__ in,
                                                  f16* __restrict__ out, int n){
    int i = (blockIdx.x*256 + threadIdx.x)*4;
    if (i < n){
        float4 v = *reinterpret_cast<const float4*>(in + i);
        f16x4 o = { (f16)v.x, (f16)v.y, (f16)v.z, (f16)v.w };
        *reinterpret_cast<f16x4*>(out + i) = o;
    }
}

// ---------------- zero-init f32 buffer ----------------
__global__ __launch_bounds__(256) void zero_kernel(float* __restrict__ p, int n){
    int i = (blockIdx.x*256 + threadIdx.x)*4;
    if (i < n){
        float4 z = {0.f,0.f,0.f,0.f};
        *reinterpret_cast<float4*>(p + i) = z;
    }
}

// ---------------- QKV projection ----------------
__global__ __launch_bounds__(256) void proj_kernel(
    const f16* __restrict__ xb, const f16* __restrict__ Wb,
    const float* __restrict__ bq, const float* __restrict__ bk, const float* __restrict__ bv,
    f16* __restrict__ Qb, f16* __restrict__ Kb, f16* __restrict__ Vt)
{
    __shared__ f16 As[128*32];
    __shared__ f16 Bs[128*32];
    const int z = blockIdx.z;
    const f16*   Wz   = Wb + (size_t)z*768*768;
    const float* bias = (z==0) ? bq : (z==1 ? bk : bv);
    f16*         out  = (z==0) ? Qb : (z==1 ? Kb : Vt);
    const int row0 = blockIdx.y*128, n0 = blockIdx.x*128;
    const int tid = threadIdx.x, w = tid>>6, l = tid&63;
    const int wm = w>>1, wn = w&1, c = l&15, g = l>>4;
    f32x4 zero = {0.f,0.f,0.f,0.f};
    f32x4 acc[4][4];
    for (int i=0;i<4;i++) for (int j=0;j<4;j++) acc[i][j] = zero;

    const f16* ag = xb + (size_t)(row0 + w*32 + (l>>2))*768 + (l&3)*8;
    const f16* bg = Wz + (size_t)(n0   + w*32 + (l>>2))*768 + (l&3)*8;
    f16* asd = As + w*1024;
    f16* bsd = Bs + w*1024;

    for (int k0 = 0; k0 < 768; k0 += 32){
        __syncthreads();
        gload16(ag + k0,          asd      );
        gload16(ag + k0 + 16*768, asd + 512);
        gload16(bg + k0,          bsd      );
        gload16(bg + k0 + 16*768, bsd + 512);
        __syncthreads();
        f16x8 af[4], bf[4];
        for (int mt=0; mt<4; mt++)
            af[mt] = *reinterpret_cast<const f16x8*>(As + (wm*64 + mt*16 + c)*32 + g*8);
        for (int nt=0; nt<4; nt++)
            bf[nt] = *reinterpret_cast<const f16x8*>(Bs + (wn*64 + nt*16 + c)*32 + g*8);
        for (int mt=0; mt<4; mt++)
            for (int nt=0; nt<4; nt++)
                acc[mt][nt] = MFMA16(af[mt], bf[nt], acc[mt][nt]);
    }

    for (int nt=0; nt<4; nt++){
        int nb = n0 + wn*64 + nt*16;
        int h  = nb/192;
        int d  = (nb - h*192) + c;
        float bv_ = bias[nb + c];
        for (int mt=0; mt<4; mt++){
            int mb = row0 + wm*64 + mt*16 + g*4;
            int bi = mb>>11, s0 = mb&2047;
            int bh = bi*4 + h;
            if (z < 2){
                int ds = d>>5, gg = (d>>3)&3, e = d&7;
                for (int r=0;r<4;r++){
                    int s = s0 + r;
                    out[ ((size_t)(bh*128 + (s>>4))*6 + ds)*512 + ((gg*16) + (s&15))*8 + e ]
                        = (f16)(acc[mt][nt][r] + bv_);
                }
            } else {
                int dt = d>>4, cV = d&15;
                int kb64 = s0>>6, ks = (s0>>5)&1, gk = (s0>>3)&3, e0 = s0&7;
                f16x4 pk = { (f16)(acc[mt][nt][0] + bv_), (f16)(acc[mt][nt][1] + bv_),
                             (f16)(acc[mt][nt][2] + bv_), (f16)(acc[mt][nt][3] + bv_) };
                *reinterpret_cast<f16x4*>(
                    &out[ ((size_t)(bh*32 + kb64)*24 + dt*2 + ks)*512 + (gk*16 + cV)*8 + e0 ]) = pk;
            }
        }
    }
}

// ================= NEW PATH =================
// pass 1: P = exp(S*SC) (masked, causal-zeroed), stored A-frag packed; L[k] += col sums.
// grid (qb=16 [128 q], ch=4 [512 k-seg], bh=16), 512 thr.
__global__ __launch_bounds__(512,4) void qkexp_kernel(
    const f16* __restrict__ Qb, const f16* __restrict__ Kb,
    const unsigned char* __restrict__ am,
    float* __restrict__ L, f16* __restrict__ Pg)
{
    __shared__ f16 Ks[2][12*512];    // 2 x 12KB (32-k K tile)
    __shared__ f16 Pl[8][16*32];     // per-wave P transpose buffer
    const int bh = blockIdx.z, b = bh>>2;
    const int qb = blockIdx.x;
    const int ch = blockIdx.y;
    if (qb < 4*ch) return;
    const int tid = threadIdx.x, w = tid>>6, l = tid&63;
    const int c = l&15, g = l>>4;
    const int qt = qb*8 + w, qw = qt*16;
    const f16* Kfm = Kb + (size_t)bh*128*6*512;
    char* Pb = (char*)(&Pl[w][0]);
    f16* pw = Pg + ((size_t)bh*4160 + poff(qt))*512 + l*8;
    float* Lb = L + bh*2048;

    f16x8 qf[6];
    {
        const f16* qbase = Qb + ((size_t)(bh*128 + qt)*6)*512 + l*8;
        for (int ds=0; ds<6; ds++) qf[ds] = *reinterpret_cast<const f16x8*>(qbase + ds*512);
    }
    bool pm[4];
    for (int r=0;r<4;r++) pm[r] = am[b*2048 + qw + g*4 + r] != 0;

    f32x4 zero = {0.f,0.f,0.f,0.f};
    const int k00  = ch*512;
    const int kend = min(ch*512 + 512, qb*128 + 128);
    const int nt   = (kend - k00) >> 5;
    const int cid  = w*3;   // waves 0..3 stage the 12 K chunks

    auto stage = [&](int buf, int k0){
        for (int i=0;i<3;i++){
            int ci = cid + i;
            if (ci < 12){
                int tl = ci/6, ds = ci - tl*6;
                gload16(Kfm + ((size_t)((k0>>4) + tl)*6 + ds)*512 + l*8, &Ks[buf][ci*512]);
            }
        }
    };

    stage(0, k00);
    __syncthreads();
    for (int it=0; it<nt; it++){
        int cur = it&1;
        int k0  = k00 + it*32;
        if (it+1 < nt) stage(cur^1, k0 + 32);

        if (k0 <= qw + 15){
            float cs[2];
            for (int kt2=0; kt2<2; kt2++){
                int kk = k0 + kt2*16;
                f32x4 sacc = zero;
                for (int ds=0; ds<6; ds++){
                    f16x8 kfr = *reinterpret_cast<const f16x8*>(&Ks[cur][(kt2*6+ds)*512 + l*8]);
                    sacc = MFMA16(qf[ds], kfr, sacc);
                }
                float csl = 0.f;
                for (int r=0;r<4;r++){
                    int q = qw + g*4 + r;
                    float v = sacc[r]*SC;
                    if (pm[r]) v = NEGV;
                    float p = __expf(v);
                    if (kk + c > q) p = 0.f;
                    csl += p;
                    int row = g*4 + r;
                    int byo = (row*64 + (kt2*16 + c)*2) ^ ((row&3)<<4);
                    *reinterpret_cast<f16*>(Pb + byo) = (f16)p;
                }
                csl += __shfl_xor(csl, 16);
                csl += __shfl_xor(csl, 32);
                cs[kt2] = csl;
            }
            // A-frag readback + global store of the 16x32 chunk
            {
                int byo = (c*64 + g*16) ^ ((c&3)<<4);
                f16x8 pa = *reinterpret_cast<const f16x8*>(Pb + byo);
                *reinterpret_cast<f16x8*>(pw + (size_t)(k0>>5)*512) = pa;
            }
            if (l < 32){
                float csv = (l < 16) ? cs[0] : cs[1];
                int kcol = k0 + ((l < 16) ? 0 : 16) + (l & 15);
                atomicAdd(&Lb[kcol], csv);
            }
        }
        __syncthreads();
    }
}

// scale V in place: V'[k,:] = V[k,:] / L[k]
__global__ __launch_bounds__(256) void scalev_kernel(f16* __restrict__ V, const float* __restrict__ L){
    int idx = blockIdx.x*256 + threadIdx.x;      // 786432 threads, 8 f16 each
    size_t base = (size_t)idx * 8;
    int bh = idx / 49152;
    int rem = idx - bh*49152;
    int chunk = rem >> 6;
    int sl = rem & 63;
    int kb64 = chunk/24, cr = chunk - kb64*24;
    int ks = cr & 1;
    int gk = sl >> 4;
    int k0 = kb64*64 + ks*32 + gk*8;
    const float* Lb = L + bh*2048 + k0;
    f16x8 v = *reinterpret_cast<f16x8*>(V + base);
    f16x8 o;
    for (int e=0;e<8;e++){
        float Lv = fmaxf(Lb[e], 1e-30f);
        o[e] = (f16)((float)v[e] / Lv);
    }
    *reinterpret_cast<f16x8*>(V + base) = o;
}

// pass 2: x1 = P @ V'  (per wave: 16 q-rows, all k; no atomics)
// grid (qbi=16, bh=16), 512 thr; qb = 15-qbi (big blocks first).
__global__ __launch_bounds__(512,4) void pv_kernel(
    const f16* __restrict__ Pg, const f16* __restrict__ Vt,
    float* __restrict__ x1)
{
    __shared__ f16 Vs[2][12*512];    // 2 x 12KB (32-k V' tile)
    const int bh = blockIdx.z, b = bh>>2, h = bh&3;
    const int qb = 15 - blockIdx.x;
    const int tid = threadIdx.x, w = tid>>6, l = tid&63;
    const int c = l&15, g = l>>4;
    const int qt = qb*8 + w, qw = qt*16;
    const f16* Vfm = Vt + (size_t)bh*32*24*512;
    const f16* pp  = Pg + ((size_t)bh*4160 + poff(qt))*512 + l*8;

    f32x4 zero = {0.f,0.f,0.f,0.f};
    f32x4 acc[12];
    for (int i=0;i<12;i++) acc[i] = zero;

    const int nt  = 4*qb + 4;       // 32-k steps covering 0..qb*128+127
    const int cid = w*3;            // waves 0..3 stage the 12 V chunks

    auto stage = [&](int buf, int k0){
        for (int i=0;i<3;i++){
            int ci = cid + i;
            if (ci < 12){
                gload16(Vfm + ((size_t)(k0>>6)*24 + ci*2 + ((k0>>5)&1))*512 + l*8, &Vs[buf][ci*512]);
            }
        }
    };

    stage(0, 0);
    __syncthreads();
    for (int it=0; it<nt; it++){
        int cur = it&1;
        int k0  = it*32;
        if (it+1 < nt) stage(cur^1, k0 + 32);

        if (k0 <= qw + 15){
            f16x8 pa = *reinterpret_cast<const f16x8*>(pp + (size_t)(k0>>5)*512);
            for (int dt=0; dt<12; dt++){
                f16x8 vb = *reinterpret_cast<const f16x8*>(&Vs[cur][dt*512 + l*8]);
                acc[dt] = MFMA16(pa, vb, acc[dt]);
            }
        }
        __syncthreads();
    }
    for (int dt=0; dt<12; dt++){
        int d = h*192 + dt*16 + c;
        for (int r=0;r<4;r++){
            int q = qw + g*4 + r;
            x1[(size_t)(b*2048 + q)*768 + d] = acc[dt][r];
        }
    }
}

// ================= R7 FALLBACK PATH (ws too small) =================
__global__ __launch_bounds__(512,4) void colstats_kernel(
    const f16* __restrict__ Qb, const f16* __restrict__ Kb,
    const unsigned char* __restrict__ am,
    float* __restrict__ Mp, float* __restrict__ Lp)
{
    __shared__ f16 Qs[2][24*512];
    const int bh = blockIdx.z, b = bh>>2;
    const int ch = blockIdx.y;
    const int kb = blockIdx.x;
    const int tid = threadIdx.x, w = tid>>6, l = tid&63;
    const int c = l&15, g = l>>4;
    const int kt = kb*128 + w*16;
    const f16* Qfm = Qb + (size_t)bh*128*6*512;
    const unsigned char* amb = am + b*2048;

    f16x8 kf[6];
    {
        const f16* kbase = Kb + ((size_t)(bh*128 + kb*8 + w)*6)*512 + l*8;
        for (int ds=0; ds<6; ds++) kf[ds] = *reinterpret_cast<const f16x8*>(kbase + ds*512);
    }

    float M = -1e38f, L = 0.f;
    f32x4 zero = {0.f,0.f,0.f,0.f};
    const int qt0 = max(ch*512, kb*128);
    const int qt1 = ch*512 + 512;
    const int nt  = (qt1 - qt0) >> 6;

    if (nt > 0){
        const int cid = w*3;
        {
            const f16* src = Qfm + ((size_t)(qt0>>4)*6 + cid)*512 + l*8;
            gload16(src,        &Qs[0][cid*512]);
            gload16(src + 512,  &Qs[0][(cid+1)*512]);
            gload16(src + 1024, &Qs[0][(cid+2)*512]);
        }
        __syncthreads();
        for (int it=0; it<nt; it++){
            int cur = it&1;
            if (it+1 < nt){
                const f16* src = Qfm + ((size_t)((qt0 + (it+1)*64)>>4)*6 + cid)*512 + l*8;
                gload16(src,        &Qs[cur^1][cid*512]);
                gload16(src + 512,  &Qs[cur^1][(cid+1)*512]);
                gload16(src + 1024, &Qs[cur^1][(cid+2)*512]);
            }
            int qt = qt0 + it*64;
            for (int j2=0; j2<4; j2++){
                int q0 = qt + j2*16;
                if (q0 + 15 < kt) continue;
                f32x4 sacc = zero;
                for (int ds=0; ds<6; ds++){
                    f16x8 qfr = *reinterpret_cast<const f16x8*>(&Qs[cur][(j2*6+ds)*512 + l*8]);
                    sacc = MFMA16(qfr, kf[ds], sacc);
                }
                float sv[4]; float m4 = -1e38f;
                for (int r=0;r<4;r++){
                    int q = q0 + g*4 + r;
                    float v = sacc[r]*SC;
                    if (amb[q]) v = NEGV;
                    if (q < kt + c) v = -1e38f;
                    sv[r] = v; m4 = fmaxf(m4, v);
                }
                m4 = fmaxf(m4, __shfl_xor(m4, 16));
                m4 = fmaxf(m4, __shfl_xor(m4, 32));
                float Mn = fmaxf(M, m4);
                float p = __expf(sv[0]-Mn) + __expf(sv[1]-Mn) + __expf(sv[2]-Mn) + __expf(sv[3]-Mn);
                p += __shfl_xor(p, 16);
                p += __shfl_xor(p, 32);
                L = L*__expf(M - Mn) + p;
                M = Mn;
            }
            __syncthreads();
        }
    }
    if (l < 16){
        size_t o = ((size_t)bh*4 + ch)*2048 + kt + l;
        Mp[o] = M;
        Lp[o] = L;
    }
}

__global__ __launch_bounds__(256) void combine_kernel(
    const float* __restrict__ Mp, const float* __restrict__ Lp,
    float* __restrict__ Mst, float* __restrict__ Lst)
{
    int idx = blockIdx.x*256 + threadIdx.x;
    int bh = idx >> 11, col = idx & 2047;
    float m[4];
    float M = -1e38f;
    for (int ch=0; ch<4; ch++){
        m[ch] = Mp[((size_t)bh*4 + ch)*2048 + col];
        M = fmaxf(M, m[ch]);
    }
    float L = 0.f;
    for (int ch=0; ch<4; ch++)
        L += Lp[((size_t)bh*4 + ch)*2048 + col] * __expf(m[ch] - M);
    Mst[(size_t)bh*2048 + col] = M;
    Lst[(size_t)bh*2048 + col] = 1.f/L;
}

__global__ __launch_bounds__(512,4) void attn_kernel(
    const f16* __restrict__ Qb, const f16* __restrict__ Kb, const f16* __restrict__ Vt,
    const float* __restrict__ Mst, const float* __restrict__ Lst,
    const unsigned char* __restrict__ am,
    float* __restrict__ x1)
{
    __shared__ f16 Ks[2][12*512];
    __shared__ f16 Vs[2][12*512];
    __shared__ f16 Pl[8][16*32];
    const int bh = blockIdx.z, b = bh>>2, h = bh&3;
    const int qb = blockIdx.x;
    const int ch = blockIdx.y;
    if (qb < 4*ch) return;
    const int tid = threadIdx.x, w = tid>>6, l = tid&63;
    const int c = l&15, g = l>>4;
    const int qw = qb*128 + w*16;
    const f16* Kfm = Kb + (size_t)bh*128*6*512;
    const f16* Vfm = Vt + (size_t)bh*32*24*512;
    const float* Mh = Mst + (size_t)bh*2048;
    const float* Lh = Lst + (size_t)bh*2048;
    char* Pb = (char*)(&Pl[w][0]);

    f16x8 qf[6];
    {
        const f16* qbase = Qb + ((size_t)(bh*128 + (qw>>4))*6)*512 + l*8;
        for (int ds=0; ds<6; ds++) qf[ds] = *reinterpret_cast<const f16x8*>(qbase + ds*512);
    }
    bool pm[4];
    for (int r=0;r<4;r++) pm[r] = am[b*2048 + qw + g*4 + r] != 0;

    f32x4 zero = {0.f,0.f,0.f,0.f};
    f32x4 acc[12];
    for (int i=0;i<12;i++) acc[i] = zero;

    const int k00  = ch*512;
    const int kend = min(ch*512 + 512, qb*128 + 128);
    const int nt   = (kend - k00) >> 5;
    const int cid = w*3;

    auto stage = [&](int buf, int k0){
        for (int i=0;i<3;i++){
            int ci = cid + i;
            if (ci < 12){
                int tl = ci/6, ds = ci - tl*6;
                gload16(Kfm + ((size_t)((k0>>4) + tl)*6 + ds)*512 + l*8, &Ks[buf][ci*512]);
            } else {
                int dt = ci - 12;
                int ks = (k0>>5)&1;
                gload16(Vfm + ((size_t)(k0>>6)*24 + dt*2 + ks)*512 + l*8, &Vs[buf][dt*512]);
            }
        }
    };

    stage(0, k00);
    __syncthreads();
    for (int it=0; it<nt; it++){
        int cur = it&1;
        int k0  = k00 + it*32;
        if (it+1 < nt) stage(cur^1, k0 + 32);

        if (k0 <= qw + 15){
            for (int kt2=0; kt2<2; kt2++){
                int kk = k0 + kt2*16;
                f32x4 sacc = zero;
                for (int ds=0; ds<6; ds++){
                    f16x8 kfr = *reinterpret_cast<const f16x8*>(&Ks[cur][(kt2*6+ds)*512 + l*8]);
                    sacc = MFMA16(qf[ds], kfr, sacc);
                }
                float Mk = Mh[kk + c], iL = Lh[kk + c];
                for (int r=0;r<4;r++){
                    int q = qw + g*4 + r;
                    float v = sacc[r]*SC;
                    if (pm[r]) v = NEGV;
                    float p = __expf(v - Mk)*iL;
                    if (kk + c > q) p = 0.f;
                    int row = g*4 + r;
                    int byo = (row*64 + (kt2*16 + c)*2) ^ ((row&3)<<4);
                    *reinterpret_cast<f16*>(Pb + byo) = (f16)p;
                }
            }
            {
                int byo = (c*64 + g*16) ^ ((c&3)<<4);
                f16x8 pa = *reinterpret_cast<const f16x8*>(Pb + byo);
                for (int dt=0; dt<12; dt++){
                    f16x8 vb = *reinterpret_cast<const f16x8*>(&Vs[cur][dt*512 + l*8]);
                    acc[dt] = MFMA16(pa, vb, acc[dt]);
                }
            }
        }
        __syncthreads();
    }
    for (int dt=0; dt<12; dt++){
        int d = h*192 + dt*16 + c;
        for (int r=0;r<4;r++){
            int q = qw + g*4 + r;
            atomicAdd(&x1[(size_t)(b*2048 + q)*768 + d], acc[dt][r]);
        }
    }
}

// ---------------- residual + layernorm ----------------
__global__ __launch_bounds__(256) void ln_kernel(
    const float* __restrict__ x, const float* __restrict__ x1,
    const float* __restrict__ gamma, const float* __restrict__ beta,
    float* __restrict__ out)
{
    const int r = blockIdx.x, t = threadIdx.x;
    const float* xr = x  + (size_t)r*768;
    const float* yr = x1 + (size_t)r*768;
    float v[3]; float s1 = 0.f, s2 = 0.f;
    for (int i=0;i<3;i++){ int j = t + i*256; float y = xr[j] + yr[j]; v[i]=y; s1+=y; s2+=y*y; }
    for (int o=32;o>=1;o>>=1){ s1 += __shfl_xor(s1,o); s2 += __shfl_xor(s2,o); }
    __shared__ float a1[4], a2[4];
    if ((t&63)==0){ a1[t>>6]=s1; a2[t>>6]=s2; }
    __syncthreads();
    s1 = a1[0]+a1[1]+a1[2]+a1[3];
    s2 = a2[0]+a2[1]+a2[2]+a2[3];
    float mu  = s1*(1.f/768.f);
    float var = s2*(1.f/768.f) - mu*mu;
    float rs  = rsqrtf(var + 1e-5f);
    for (int i=0;i<3;i++){
        int j = t + i*256;
        out[(size_t)r*768 + j] = (v[i]-mu)*rs*gamma[j] + beta[j];
    }
}

extern "C" void kernel_launch(void* const* d_in, const int* in_sizes, int n_in,
                              void* d_out, int out_size, void* d_ws, size_t ws_size,
                              hipStream_t stream)
{
    const float* x     = (const float*)d_in[0];
    const unsigned char* am = (const unsigned char*)d_in[1];
    const float* Wq    = (const float*)d_in[2];
    const float* bq    = (const float*)d_in[3];
    const float* Wk    = (const float*)d_in[4];
    const float* bk    = (const float*)d_in[5];
    const float* Wv    = (const float*)d_in[6];
    const float* bv    = (const float*)d_in[7];
    const float* gamma = (const float*)d_in[8];
    const float* beta  = (const float*)d_in[9];
    float* out = (float*)d_out;

    f16* xb  = (f16*)d_ws;                     // 12,582,912 B
    f16* Wb  = xb + (size_t)8192*768;          // +3,538,944
    f16* Qb  = Wb + (size_t)3*768*768;         // +12,582,912
    f16* Kb  = Qb + (size_t)16*2048*192;       // +12,582,912
    f16* Vt  = Kb + (size_t)16*2048*192;       // +12,582,912
    f16* Pg  = Vt + (size_t)16*2048*192;       // +68,157,440  (new path)
    const size_t NEED_NEW = 12582912ULL + 3538944 + 3*12582912 + 68157440;

    cvt_kernel<<<6144, 256, 0, stream>>>(x,  xb, 8192*768);
    cvt_kernel<<<576,  256, 0, stream>>>(Wq, Wb,            589824);
    cvt_kernel<<<576,  256, 0, stream>>>(Wk, Wb + 589824,   589824);
    cvt_kernel<<<576,  256, 0, stream>>>(Wv, Wb + 2*589824, 589824);
    proj_kernel<<<dim3(6,64,3), 256, 0, stream>>>(xb, Wb, bq, bk, bv, Qb, Kb, Vt);

    if (ws_size >= NEED_NEW){
        // L aliases xb (dead after proj); x1 aliases Qb+Kb (dead after qkexp)
        float* L  = (float*)xb;
        float* x1 = (float*)Qb;
        zero_kernel<<<32, 256, 0, stream>>>(L, 16*2048);
        qkexp_kernel<<<dim3(16,4,16), 512, 0, stream>>>(Qb, Kb, am, L, Pg);
        scalev_kernel<<<3072, 256, 0, stream>>>(Vt, L);
        pv_kernel<<<dim3(16,1,16), 512, 0, stream>>>(Pg, Vt, x1);
        ln_kernel<<<8192, 256, 0, stream>>>(x, x1, gamma, beta, out);
    } else {
        // R7 fallback
        float* Mst = (float*)(Vt + (size_t)16*2048*192);
        float* Lst = Mst + 16*2048;
        float* x1  = Lst + 16*2048;
        float* Mp  = (float*)xb;
        float* Lp  = Mp + 16*4*2048;
        colstats_kernel<<<dim3(16,4,16), 512, 0, stream>>>(Qb, Kb, am, Mp, Lp);
        combine_kernel<<<128, 256, 0, stream>>>(Mp, Lp, Mst, Lst);
        zero_kernel<<<6144, 256, 0, stream>>>(x1, 8192*768);
        attn_kernel<<<dim3(16,4,16), 512, 0, stream>>>(Qb, Kb, Vt, Mst, Lst, am, x1);
        ln_kernel<<<8192, 256, 0, stream>>>(x, x1, gamma, beta, out);
    }
}